// Round 9
// baseline (216.021 us; speedup 1.0000x reference)
//
#include <hip/hip_runtime.h>
#include <cstdint>

#define NN 8192
#define NE 65536
#define G 8     // nodes per block in nodeprep (1024 blocks)
#define CAP 64  // bucket capacity per CSR row (Poisson λ=8 -> P(deg>64) ~ 0)

typedef _Float16 h8 __attribute__((ext_vector_type(8)));
typedef _Float16 h2 __attribute__((ext_vector_type(2)));

__device__ inline int rdlane_i(int v, int l) {
  return __builtin_amdgcn_readlane(v, l);
}
__device__ inline float rdlane_f(float v, int l) {
  return __int_as_float(__builtin_amdgcn_readlane(__float_as_int(v), l));
}

// ---------- Threefry-2x32, 20 rounds, JAX-compatible ----------
__host__ __device__ inline void tf2x32(uint32_t k0, uint32_t k1,
                                       uint32_t x0, uint32_t x1,
                                       uint32_t& r0, uint32_t& r1) {
  uint32_t ks2 = k0 ^ k1 ^ 0x1BD11BDAu;
  x0 += k0; x1 += k1;
#define TF_ROT(x,d) (((x)<<(d))|((x)>>(32-(d))))
#define TF_R4(ra,rb,rc,rd) \
  x0+=x1; x1=TF_ROT(x1,ra); x1^=x0; \
  x0+=x1; x1=TF_ROT(x1,rb); x1^=x0; \
  x0+=x1; x1=TF_ROT(x1,rc); x1^=x0; \
  x0+=x1; x1=TF_ROT(x1,rd); x1^=x0;
  TF_R4(13,15,26,6)  x0+=k1;  x1+=ks2+1u;
  TF_R4(17,29,16,24) x0+=ks2; x1+=k0+2u;
  TF_R4(13,15,26,6)  x0+=k0;  x1+=k1+3u;
  TF_R4(17,29,16,24) x0+=k1;  x1+=ks2+4u;
  TF_R4(13,15,26,6)  x0+=ks2; x1+=k0+5u;
  r0=x0; r1=x1;
#undef TF_R4
#undef TF_ROT
}

__device__ inline float gumbel32(uint32_t k0, uint32_t k1, uint32_t idx) {
  uint32_t a, b;
  tf2x32(k0, k1, 0u, idx, a, b);
  uint32_t bits = a ^ b;
  float f = __uint_as_float((bits >> 9) | 0x3f800000u) - 1.0f;
  float u = (f > 0.0f) ? f : 1.17549435e-38f;
  return -logf(-logf(u));
}

// ---------- per-node precompute + layer-0 gates + edge scatter (8 nodes/block) ----------
__global__ __launch_bounds__(256) void k_nodeprep(
    const float* __restrict__ x, const float* __restrict__ ipw,
    const float* __restrict__ xpw, const float* __restrict__ dtw,
    const float* __restrict__ iaw, const float* __restrict__ iab,
    const float* __restrict__ oaw, const float* __restrict__ oab,
    const float* __restrict__ alog, const float* __restrict__ wout,
    const int* __restrict__ ei,
    uint32_t ki0, uint32_t ki1, uint32_t ko0, uint32_t ko1,
    float* __restrict__ xs, float* __restrict__ rres,
    float* __restrict__ delta, _Float16* __restrict__ dxh2,
    float* __restrict__ Bm, float* __restrict__ Cm,
    float* __restrict__ inp, float* __restrict__ outp,
    float* __restrict__ Amat, _Float16* __restrict__ woT,
    int* __restrict__ cnt, int* __restrict__ csr_col) {
  __shared__ float sxs[G][128];
  __shared__ float sdbl[G][36];
  __shared__ float sdx[G][128];
  int t = threadIdx.x;
  int b0 = blockIdx.x * G;
  // fused edge scatter: 64 edges per block (1024 blocks x 64 = NE)
  if (t < 64) {
    int e = blockIdx.x * 64 + t;
    int v = ei[e];
    int pos = atomicAdd(&cnt[v], 1);
    if (pos < CAP) csr_col[(v<<6) + pos] = ei[NE + e];
  }
  // wout -> fp16, TRANSPOSED to [oc][d] for the projection
  {
    int i = blockIdx.x * 8 + (t & 7);
    if (t < 8) {
      int d = i >> 6, oc = i & 63;
      woT[oc*128 + d] = (_Float16)wout[i];
    }
  }
  if (blockIdx.x == 0) {
    for (int i = t; i < 2048; i += 256) Amat[i] = -expf(alog[i]);
  }
  // GEMM1: [G x 64] @ [64 x 256]; x rows via wave-uniform (scalar) loads
  float acc[G];
#pragma unroll
  for (int g = 0; g < G; g++) acc[g] = 0.f;
  const float4* xb = (const float4*)(x + (size_t)b0 * 64);
  for (int k4 = 0; k4 < 16; k4++) {
    float w0 = ipw[(k4*4+0)*256 + t];
    float w1 = ipw[(k4*4+1)*256 + t];
    float w2 = ipw[(k4*4+2)*256 + t];
    float w3 = ipw[(k4*4+3)*256 + t];
#pragma unroll
    for (int g = 0; g < G; g++) {
      float4 xv = xb[g*16 + k4];   // uniform address -> s_load_dwordx4
      acc[g] += xv.x*w0; acc[g] += xv.y*w1; acc[g] += xv.z*w2; acc[g] += xv.w*w3;
    }
  }
  if (t < 128) {
#pragma unroll
    for (int g = 0; g < G; g++) {
      float v = fmaxf(acc[g], 0.f);
      sxs[g][t] = v;
      xs[(size_t)(b0+g)*128 + t] = v;
    }
  } else {
    int j = t - 128;
#pragma unroll
    for (int g = 0; g < G; g++) rres[(size_t)(b0+g)*128 + j] = fmaxf(acc[g], 0.f);
  }
  __syncthreads();
  // GEMM2: x_dbl [G x 36], sxs read as float4 (broadcast b128)
  for (int idx = t; idx < G*36; idx += 256) {
    int g = idx / 36, c = idx % 36;
    float a = 0.f;
    for (int d4 = 0; d4 < 32; d4++) {
      float4 sv = ((const float4*)&sxs[g][0])[d4];
      a += sv.x*xpw[(d4*4+0)*36 + c];
      a += sv.y*xpw[(d4*4+1)*36 + c];
      a += sv.z*xpw[(d4*4+2)*36 + c];
      a += sv.w*xpw[(d4*4+3)*36 + c];
    }
    sdbl[g][c] = a;
    if (c >= 4 && c < 20)  Bm[(b0+g)*16 + (c-4)]  = a;
    else if (c >= 20)      Cm[(b0+g)*16 + (c-20)] = a;
  }
  __syncthreads();
  // GEMM3: softplus(delta) + dxs -> sdx
  {
    int d = t & 127, hi = t >> 7;
#pragma unroll
    for (int gg = 0; gg < G/2; gg++) {
      int g = hi*(G/2) + gg;
      int b = b0 + g;
      float dt = sdbl[g][0]*dtw[d]     + sdbl[g][1]*dtw[128+d]
               + sdbl[g][2]*dtw[256+d] + sdbl[g][3]*dtw[384+d];
      float dv = fmaxf(dt, 0.f) + log1pf(expf(-fabsf(dt)));  // softplus
      delta[(size_t)b*128 + d] = dv;
      sdx[g][d] = dv * sxs[g][d];
    }
  }
  __syncthreads();
  // dxh2 pack + gates (one node per wave per step, wave-local)
  for (int i = t; i < G*64; i += 256) {
    int g = i >> 6, d = i & 63;
    h2 pk;
    pk.x = (_Float16)sdx[g][d];
    pk.y = (_Float16)sdx[g][d + 64];
    ((h2*)(dxh2 + ((size_t)(b0+g) << 7)))[d] = pk;
  }
  int wid = t >> 6, lane = t & 63;
#pragma unroll
  for (int s = 0; s < 2; s++) {
    int g = wid*2 + s;
    int b = b0 + g;
    float da = sdx[g][lane], db = sdx[g][lane + 64];
    float4 pr;
    pr.x = da*iaw[2*lane]   + db*iaw[2*(lane+64)];
    pr.y = da*iaw[2*lane+1] + db*iaw[2*(lane+64)+1];
    pr.z = da*oaw[2*lane]   + db*oaw[2*(lane+64)];
    pr.w = da*oaw[2*lane+1] + db*oaw[2*(lane+64)+1];
    for (int off = 32; off >= 1; off >>= 1) {
      pr.x += __shfl_down(pr.x, off);
      pr.y += __shfl_down(pr.y, off);
      pr.z += __shfl_down(pr.z, off);
      pr.w += __shfl_down(pr.w, off);
    }
    // 4 gumbels on 4 parallel lanes; bit-identical tf2x32 inputs
    float gsel = 0.f;
    if (lane < 4) {
      uint32_t kk0 = (lane < 2) ? ki0 : ko0;
      uint32_t kk1 = (lane < 2) ? ki1 : ko1;
      gsel = gumbel32(kk0, kk1, 2u*(uint32_t)b + (uint32_t)(lane & 1));
    }
    float g0 = __shfl(gsel, 0), g1 = __shfl(gsel, 1);
    float g2 = __shfl(gsel, 2), g3 = __shfl(gsel, 3);
    if (lane == 0) {
      float BC = 0.f;
      for (int n = 0; n < 16; n++) BC += sdbl[g][4+n] * sdbl[g][20+n];
      float li0 = BC*pr.x + iab[0], li1 = BC*pr.y + iab[1];
      float lo0 = BC*pr.z + oab[0], lo1 = BC*pr.w + oab[1];
      inp[b]  = (li0 + g0 >= li1 + g1) ? 1.0f : 0.0f;
      outp[b] = (lo0 + g2 >= lo1 + g3) ? 1.0f : 0.0f;
    }
  }
}

// ---------- spmm0 + layer-1 update + deg1 + layer-2 self-term ----------
// ONE WAVE PER NODE. __launch_bounds__(256,8) forces <=64 VGPR -> 8 waves/SIMD
// (was ~6); neighbor loop padded to a multiple of 8 + unroll 8 so a typical
// deg~8 node issues its whole gather sequence before the first stall.
__global__ __launch_bounds__(256, 8) void k_spmm0f(
    const int* __restrict__ cnt, const int* __restrict__ csr_col,
    const float* __restrict__ inp, const float* __restrict__ outp,
    const float* __restrict__ delta, const _Float16* __restrict__ dxh2,
    const float* __restrict__ Bm, const float* __restrict__ Cm,
    const float* __restrict__ Amat,
    _Float16* __restrict__ s_out, float* __restrict__ dinv1,
    float* __restrict__ y2p) {
  int t = threadIdx.x, wid = t >> 6, lane = t & 63;
  int v = (blockIdx.x << 2) + wid;
  int deg = min(cnt[v], CAP);
  float inpv = inp[v];      // wave-uniform -> SGPR; in flight during gather loop
  float outpv = outp[v];
  int   creg = 0;
  float cfreg = 0.f, gl = 0.f;
  if (lane < deg) {
    creg = csr_col[(v << 6) + lane];
    cfreg = 1.0f / sqrtf((float)min(cnt[creg], CAP) + 1.0f);
    gl = inp[creg];
  }
  float degs = gl;
#pragma unroll
  for (int off = 32; off >= 1; off >>= 1) degs += __shfl_xor(degs, off);
  int d0 = lane, d1 = lane + 64;
  float dv = 1.0f / sqrtf((float)deg + 1.0f);
  h2 pkv = ((const h2*)(dxh2 + ((size_t)v << 7)))[d0];
  float dx0 = (float)pkv.x, dx1 = (float)pkv.y;
  // self-node B row (wave-uniform address -> scalar loads / SGPRs)
  float Bf[16];
  {
    const float4* p = (const float4*)(Bm + ((size_t)v << 4));
    float4 q0 = p[0], q1 = p[1], q2 = p[2], q3 = p[3];
    Bf[0]=q0.x; Bf[1]=q0.y; Bf[2]=q0.z; Bf[3]=q0.w;
    Bf[4]=q1.x; Bf[5]=q1.y; Bf[6]=q1.z; Bf[7]=q1.w;
    Bf[8]=q2.x; Bf[9]=q2.y; Bf[10]=q2.z; Bf[11]=q2.w;
    Bf[12]=q3.x; Bf[13]=q3.y; Bf[14]=q3.z; Bf[15]=q3.w;
  }
  float a0[16], a1[16];
  {
    float dw = dv * dv;
    float c0 = dw * dx0, c1 = dw * dx1;
#pragma unroll
    for (int n = 0; n < 16; n++) { a0[n] = c0*Bf[n]; a1[n] = c1*Bf[n]; }
  }
  int jmax = (deg + 7) & ~7;   // padded: cf=0 slots are exact no-ops
#pragma unroll 8
  for (int j = 0; j < jmax; j++) {
    int   c  = rdlane_i(creg, j);          // SGPR-uniform neighbor id (0 on pad)
    float cf = rdlane_f(cfreg, j);         // 0 on pad
    float coef = dv * cf;
    h2 pk = ((const h2*)(dxh2 + ((size_t)c << 7)))[d0];
    const float4* bp = (const float4*)(Bm + ((size_t)c << 4));  // uniform -> s_load
    float4 B0 = bp[0], B1 = bp[1], B2 = bp[2], B3 = bp[3];
    float e0 = coef * (float)pk.x;
    float e1 = coef * (float)pk.y;
    a0[0]+=e0*B0.x; a0[1]+=e0*B0.y; a0[2]+=e0*B0.z; a0[3]+=e0*B0.w;
    a0[4]+=e0*B1.x; a0[5]+=e0*B1.y; a0[6]+=e0*B1.z; a0[7]+=e0*B1.w;
    a0[8]+=e0*B2.x; a0[9]+=e0*B2.y; a0[10]+=e0*B2.z; a0[11]+=e0*B2.w;
    a0[12]+=e0*B3.x; a0[13]+=e0*B3.y; a0[14]+=e0*B3.z; a0[15]+=e0*B3.w;
    a1[0]+=e1*B0.x; a1[1]+=e1*B0.y; a1[2]+=e1*B0.z; a1[3]+=e1*B0.w;
    a1[4]+=e1*B1.x; a1[5]+=e1*B1.y; a1[6]+=e1*B1.z; a1[7]+=e1*B1.w;
    a1[8]+=e1*B2.x; a1[9]+=e1*B2.y; a1[10]+=e1*B2.z; a1[11]+=e1*B2.w;
    a1[12]+=e1*B3.x; a1[13]+=e1*B3.y; a1[14]+=e1*B3.z; a1[15]+=e1*B3.w;
  }
  float de0 = delta[(size_t)v*128 + d0], de1 = delta[(size_t)v*128 + d1];
  const float4* A0p = (const float4*)(Amat + (d0 << 4));
  const float4* A1p = (const float4*)(Amat + (d1 << 4));
  const float4* Cp  = (const float4*)(Cm + ((size_t)v << 4));
  float d1v = 1.0f / sqrtf(outpv*degs + 1.0f);
  if (lane == 0) dinv1[v] = d1v;
  float dw1 = d1v * d1v;
  float y0 = 0.f, y1 = 0.f, BvC = 0.f;
  _Float16 sh0[16], sh1[16];
#pragma unroll
  for (int q = 0; q < 4; q++) {
    float4 Aq0 = A0p[q], Aq1 = A1p[q], Cq = Cp[q];
    float A0a[4] = {Aq0.x, Aq0.y, Aq0.z, Aq0.w};
    float A1a[4] = {Aq1.x, Aq1.y, Aq1.z, Aq1.w};
    float Ca[4]  = {Cq.x, Cq.y, Cq.z, Cq.w};
#pragma unroll
    for (int i = 0; i < 4; i++) {
      int n = 4*q + i;
      float E0 = expf(de0 * A0a[i]);
      float E1 = expf(de1 * A1a[i]);
      float s0 = E0*a0[n] + dx0*Bf[n];
      float s1 = E1*a1[n] + dx1*Bf[n];
      y0 += E0*s0*Ca[i];
      y1 += E1*s1*Ca[i];
      BvC += Bf[n]*Ca[i];
      sh0[n] = (_Float16)s0;
      sh1[n] = (_Float16)s1;
    }
  }
  y0 = dw1*y0 + dx0*BvC;
  y1 = dw1*y1 + dx1*BvC;
  if (inpv != 0.f) {
    h8 P00, P01, P10, P11;
#pragma unroll
    for (int i = 0; i < 8; i++) {
      P00[i] = sh0[i]; P01[i] = sh0[8+i];
      P10[i] = sh1[i]; P11[i] = sh1[8+i];
    }
    h8* op = (h8*)(s_out + ((size_t)v << 11));
    op[2*lane]           = P00;
    op[2*lane + 1]       = P01;
    op[128 + 2*lane]     = P10;
    op[128 + 2*lane + 1] = P11;
  }
  y2p[(size_t)v*128 + d0] = y0;
  y2p[(size_t)v*128 + d1] = y1;
}

// ---------- gated spmm1 + layer-2 + output projection ----------
// ONE WAVE PER NODE. __launch_bounds__(256,8) -> 8 waves/SIMD. Per-wave LDS
// compaction of ACTIVE neighbors -> dense branch-free padded loop.
__global__ __launch_bounds__(256, 8) void k_spmm1fo(
    const int* __restrict__ cnt, const int* __restrict__ csr_col,
    const float* __restrict__ dinv1,
    const float* __restrict__ inp, const float* __restrict__ outp,
    const float* __restrict__ delta,
    const float* __restrict__ Cm, const float* __restrict__ Amat,
    const _Float16* __restrict__ s_in, const float* __restrict__ y2p,
    const float* __restrict__ xs, const float* __restrict__ rres,
    const float* __restrict__ Dv, const _Float16* __restrict__ woT,
    float* __restrict__ out) {
  __shared__ float ty[4][128];
  __shared__ int   scn[4];
  __shared__ int   scc[4][CAP];
  __shared__ float scf[4][CAP];
  int t = threadIdx.x, wid = t >> 6, lane = t & 63;
  int v = (blockIdx.x << 2) + wid;
  int deg = (outp[v] != 0.f) ? min(cnt[v], CAP) : 0;
  if (lane == 0) scn[wid] = 0;          // same-wave LDS ordering: write < atomics
  if (lane < deg) {
    int c = csr_col[(v << 6) + lane];
    float g = inp[c];
    if (g != 0.f) {
      int p = atomicAdd(&scn[wid], 1);  // wave-local compaction
      scc[wid][p] = c;
      scf[wid][p] = dinv1[c];
    }
  }
  asm volatile("s_waitcnt lgkmcnt(0)" ::: "memory");
  int nact = scn[wid];
  int   creg = 0;
  float cfreg = 0.f;
  if (nact > 0) {
    creg = scc[wid][(lane < nact) ? lane : 0];  // pad slots -> first ACTIVE row
    if (lane < nact) cfreg = scf[wid][lane];    // pad coef = 0
  }
  int d0 = lane, d1 = lane + 64;
  float y0 = 0.f, y1 = 0.f;
  if (nact > 0) {
    float dvv = dinv1[v];
    float a0[16], a1[16];
#pragma unroll
    for (int n = 0; n < 16; n++) { a0[n] = 0.f; a1[n] = 0.f; }
    int jmax = (nact + 3) & ~3;
#pragma unroll 4
    for (int j = 0; j < jmax; j++) {
      int   c  = rdlane_i(creg, j);
      float cf = rdlane_f(cfreg, j);
      float coef = dvv * cf;
      const h8* rp = (const h8*)(s_in + ((size_t)c << 11));
      h8 n00 = rp[2*lane], n01 = rp[2*lane+1];
      h8 n10 = rp[128 + 2*lane], n11 = rp[128 + 2*lane+1];
      a0[0]+=coef*(float)n00[0]; a0[1]+=coef*(float)n00[1];
      a0[2]+=coef*(float)n00[2]; a0[3]+=coef*(float)n00[3];
      a0[4]+=coef*(float)n00[4]; a0[5]+=coef*(float)n00[5];
      a0[6]+=coef*(float)n00[6]; a0[7]+=coef*(float)n00[7];
      a0[8]+=coef*(float)n01[0]; a0[9]+=coef*(float)n01[1];
      a0[10]+=coef*(float)n01[2]; a0[11]+=coef*(float)n01[3];
      a0[12]+=coef*(float)n01[4]; a0[13]+=coef*(float)n01[5];
      a0[14]+=coef*(float)n01[6]; a0[15]+=coef*(float)n01[7];
      a1[0]+=coef*(float)n10[0]; a1[1]+=coef*(float)n10[1];
      a1[2]+=coef*(float)n10[2]; a1[3]+=coef*(float)n10[3];
      a1[4]+=coef*(float)n10[4]; a1[5]+=coef*(float)n10[5];
      a1[6]+=coef*(float)n10[6]; a1[7]+=coef*(float)n10[7];
      a1[8]+=coef*(float)n11[0]; a1[9]+=coef*(float)n11[1];
      a1[10]+=coef*(float)n11[2]; a1[11]+=coef*(float)n11[3];
      a1[12]+=coef*(float)n11[4]; a1[13]+=coef*(float)n11[5];
      a1[14]+=coef*(float)n11[6]; a1[15]+=coef*(float)n11[7];
    }
    float de0 = delta[(size_t)v*128 + d0], de1 = delta[(size_t)v*128 + d1];
    const float4* A0p = (const float4*)(Amat + (d0 << 4));
    const float4* A1p = (const float4*)(Amat + (d1 << 4));
    const float4* Cp  = (const float4*)(Cm + ((size_t)v << 4));
#pragma unroll
    for (int q = 0; q < 4; q++) {
      float4 Aq0 = A0p[q], Aq1 = A1p[q], Cq = Cp[q];
      float A0a[4] = {Aq0.x, Aq0.y, Aq0.z, Aq0.w};
      float A1a[4] = {Aq1.x, Aq1.y, Aq1.z, Aq1.w};
      float Ca[4]  = {Cq.x, Cq.y, Cq.z, Cq.w};
#pragma unroll
      for (int i = 0; i < 4; i++) {
        int n = 4*q + i;
        y0 += expf(de0*A0a[i]) * a0[n] * Ca[i];
        y1 += expf(de1*A1a[i]) * a1[n] * Ca[i];
      }
    }
  }
  float t0 = (y0 + y2p[(size_t)v*128 + d0] + xs[(size_t)v*128 + d0]*Dv[d0]) * rres[(size_t)v*128 + d0];
  float t1 = (y1 + y2p[(size_t)v*128 + d1] + xs[(size_t)v*128 + d1]*Dv[d1]) * rres[(size_t)v*128 + d1];
  ty[wid][d0] = t0;
  ty[wid][d1] = t1;
  asm volatile("s_waitcnt lgkmcnt(0)" ::: "memory");   // wave's ty writes complete
  __builtin_amdgcn_sched_barrier(0);
  // projection: lane = oc; ty broadcast reads (b128) + 16 h8 woT row loads (L1-resident)
  float acc = 0.f;
  const float4* tyv = (const float4*)&ty[wid][0];
  const h8* wrow = (const h8*)(woT + ((size_t)lane << 7));
#pragma unroll
  for (int ch = 0; ch < 16; ch++) {
    h8 wv = wrow[ch];
    float4 u0 = tyv[2*ch], u1 = tyv[2*ch+1];
    acc += u0.x*(float)wv[0] + u0.y*(float)wv[1] + u0.z*(float)wv[2] + u0.w*(float)wv[3]
         + u1.x*(float)wv[4] + u1.y*(float)wv[5] + u1.z*(float)wv[6] + u1.w*(float)wv[7];
  }
  out[(size_t)v*64 + lane] = acc;
}

extern "C" void kernel_launch(void* const* d_in, const int* in_sizes, int n_in,
                              void* d_out, int out_size, void* d_ws, size_t ws_size,
                              hipStream_t stream) {
  const float* x    = (const float*)d_in[0];
  const float* ipw  = (const float*)d_in[1];
  const float* xpw  = (const float*)d_in[2];
  const float* dtw  = (const float*)d_in[3];
  const float* alog = (const float*)d_in[4];
  const float* Dv   = (const float*)d_in[5];
  const float* wout = (const float*)d_in[6];
  const float* iaw  = (const float*)d_in[7];
  const float* iab  = (const float*)d_in[8];
  const float* oaw  = (const float*)d_in[9];
  const float* oab  = (const float*)d_in[10];
  const int*   ei   = (const int*)d_in[11];
  (void)in_sizes; (void)n_in; (void)out_size; (void)ws_size;

  float* W = (float*)d_ws;
  size_t o = 0;
  float* xs    = W + o; o += (size_t)NN*128;
  float* rres  = W + o; o += (size_t)NN*128;
  float* delta = W + o; o += (size_t)NN*128;
  float* y2p   = W + o; o += (size_t)NN*128;
  float* Bm    = W + o; o += (size_t)NN*16;
  float* Cm    = W + o; o += (size_t)NN*16;
  float* Amat  = W + o; o += 2048;
  float* dinv1 = W + o; o += NN;
  float* inp   = W + o; o += NN;
  float* outp  = W + o; o += NN;
  _Float16* dxh2 = (_Float16*)(W + o); o += (size_t)NN*64;   // 2 MB
  o += (size_t)NN*8;                                          // (reserved slot)
  _Float16* woT  = (_Float16*)(W + o); o += 4096;            // 16 KB (8192 h, transposed [oc][d])
  _Float16* stA  = (_Float16*)(W + o); o += (size_t)NN*1024; // fp16 state1, 32 MB
  int* cnt     = (int*)(W + o);
  int* csr_col = cnt + NN;

  uint32_t ki0, ki1, ko0, ko1;
  tf2x32(0u, 42u, 0u, 0u, ki0, ki1);
  tf2x32(0u, 42u, 0u, 1u, ko0, ko1);

  // zero CSR counters; scatter is fused into k_nodeprep
  hipMemsetAsync(cnt, 0, NN*sizeof(int), stream);

  // per-node precompute + layer-0 gates + Amat + woT + edge scatter
  k_nodeprep<<<NN/G, 256, 0, stream>>>(x, ipw, xpw, dtw, iaw, iab, oaw, oab,
                                       alog, wout, ei, ki0, ki1, ko0, ko1,
                                       xs, rres, delta, dxh2, Bm, Cm,
                                       inp, outp, Amat, woT, cnt, csr_col);

  // spmm0; one wave/node, 8 waves/SIMD forced, unroll-8 padded pipeline
  k_spmm0f<<<NN/4, 256, 0, stream>>>(cnt, csr_col, inp, outp,
                                     delta, dxh2, Bm, Cm, Amat,
                                     stA, dinv1, y2p);

  // gated spmm1 + projection; one wave/node, 8 waves/SIMD forced
  k_spmm1fo<<<NN/4, 256, 0, stream>>>(cnt, csr_col, dinv1, inp, outp,
                                      delta, Cm, Amat, stA, y2p,
                                      xs, rres, Dv, woT, (float*)d_out);
}

// Round 10
// 155.901 us; speedup vs baseline: 1.3856x; 1.3856x over previous
//
#include <hip/hip_runtime.h>
#include <cstdint>

#define NN 8192
#define NE 65536
#define G 8     // nodes per block in nodeprep (1024 blocks)
#define CAP 64  // bucket capacity per CSR row (Poisson λ=8 -> P(deg>64) ~ 0)

typedef _Float16 h8 __attribute__((ext_vector_type(8)));
typedef _Float16 h2 __attribute__((ext_vector_type(2)));

__device__ inline int rdlane_i(int v, int l) {
  return __builtin_amdgcn_readlane(v, l);
}
__device__ inline float rdlane_f(float v, int l) {
  return __int_as_float(__builtin_amdgcn_readlane(__float_as_int(v), l));
}

// ---------- Threefry-2x32, 20 rounds, JAX-compatible ----------
__host__ __device__ inline void tf2x32(uint32_t k0, uint32_t k1,
                                       uint32_t x0, uint32_t x1,
                                       uint32_t& r0, uint32_t& r1) {
  uint32_t ks2 = k0 ^ k1 ^ 0x1BD11BDAu;
  x0 += k0; x1 += k1;
#define TF_ROT(x,d) (((x)<<(d))|((x)>>(32-(d))))
#define TF_R4(ra,rb,rc,rd) \
  x0+=x1; x1=TF_ROT(x1,ra); x1^=x0; \
  x0+=x1; x1=TF_ROT(x1,rb); x1^=x0; \
  x0+=x1; x1=TF_ROT(x1,rc); x1^=x0; \
  x0+=x1; x1=TF_ROT(x1,rd); x1^=x0;
  TF_R4(13,15,26,6)  x0+=k1;  x1+=ks2+1u;
  TF_R4(17,29,16,24) x0+=ks2; x1+=k0+2u;
  TF_R4(13,15,26,6)  x0+=k0;  x1+=k1+3u;
  TF_R4(17,29,16,24) x0+=k1;  x1+=ks2+4u;
  TF_R4(13,15,26,6)  x0+=ks2; x1+=k0+5u;
  r0=x0; r1=x1;
#undef TF_R4
#undef TF_ROT
}

__device__ inline float gumbel32(uint32_t k0, uint32_t k1, uint32_t idx) {
  uint32_t a, b;
  tf2x32(k0, k1, 0u, idx, a, b);
  uint32_t bits = a ^ b;
  float f = __uint_as_float((bits >> 9) | 0x3f800000u) - 1.0f;
  float u = (f > 0.0f) ? f : 1.17549435e-38f;
  return -logf(-logf(u));
}

// ---------- per-node precompute + layer-0 gates + edge scatter (8 nodes/block) ----------
__global__ __launch_bounds__(256) void k_nodeprep(
    const float* __restrict__ x, const float* __restrict__ ipw,
    const float* __restrict__ xpw, const float* __restrict__ dtw,
    const float* __restrict__ iaw, const float* __restrict__ iab,
    const float* __restrict__ oaw, const float* __restrict__ oab,
    const float* __restrict__ alog, const float* __restrict__ wout,
    const int* __restrict__ ei,
    uint32_t ki0, uint32_t ki1, uint32_t ko0, uint32_t ko1,
    float* __restrict__ xs, float* __restrict__ rres,
    float* __restrict__ delta, _Float16* __restrict__ dxh2,
    float* __restrict__ Bm, float* __restrict__ Cm,
    float* __restrict__ inp, float* __restrict__ outp,
    float* __restrict__ Amat, _Float16* __restrict__ woT,
    int* __restrict__ cnt, int* __restrict__ csr_col) {
  __shared__ float sxs[G][128];
  __shared__ float sdbl[G][36];
  __shared__ float sdx[G][128];
  int t = threadIdx.x;
  int b0 = blockIdx.x * G;
  // fused edge scatter: 64 edges per block (1024 blocks x 64 = NE)
  if (t < 64) {
    int e = blockIdx.x * 64 + t;
    int v = ei[e];
    int pos = atomicAdd(&cnt[v], 1);
    if (pos < CAP) csr_col[(v<<6) + pos] = ei[NE + e];
  }
  // wout -> fp16, TRANSPOSED to [oc][d] for the projection
  {
    int i = blockIdx.x * 8 + (t & 7);
    if (t < 8) {
      int d = i >> 6, oc = i & 63;
      woT[oc*128 + d] = (_Float16)wout[i];
    }
  }
  if (blockIdx.x == 0) {
    for (int i = t; i < 2048; i += 256) Amat[i] = -expf(alog[i]);
  }
  // GEMM1: [G x 64] @ [64 x 256]; x rows via wave-uniform (scalar) loads
  float acc[G];
#pragma unroll
  for (int g = 0; g < G; g++) acc[g] = 0.f;
  const float4* xb = (const float4*)(x + (size_t)b0 * 64);
  for (int k4 = 0; k4 < 16; k4++) {
    float w0 = ipw[(k4*4+0)*256 + t];
    float w1 = ipw[(k4*4+1)*256 + t];
    float w2 = ipw[(k4*4+2)*256 + t];
    float w3 = ipw[(k4*4+3)*256 + t];
#pragma unroll
    for (int g = 0; g < G; g++) {
      float4 xv = xb[g*16 + k4];   // uniform address -> s_load_dwordx4
      acc[g] += xv.x*w0; acc[g] += xv.y*w1; acc[g] += xv.z*w2; acc[g] += xv.w*w3;
    }
  }
  if (t < 128) {
#pragma unroll
    for (int g = 0; g < G; g++) {
      float v = fmaxf(acc[g], 0.f);
      sxs[g][t] = v;
      xs[(size_t)(b0+g)*128 + t] = v;
    }
  } else {
    int j = t - 128;
#pragma unroll
    for (int g = 0; g < G; g++) rres[(size_t)(b0+g)*128 + j] = fmaxf(acc[g], 0.f);
  }
  __syncthreads();
  // GEMM2: x_dbl [G x 36], sxs read as float4 (broadcast b128)
  for (int idx = t; idx < G*36; idx += 256) {
    int g = idx / 36, c = idx % 36;
    float a = 0.f;
    for (int d4 = 0; d4 < 32; d4++) {
      float4 sv = ((const float4*)&sxs[g][0])[d4];
      a += sv.x*xpw[(d4*4+0)*36 + c];
      a += sv.y*xpw[(d4*4+1)*36 + c];
      a += sv.z*xpw[(d4*4+2)*36 + c];
      a += sv.w*xpw[(d4*4+3)*36 + c];
    }
    sdbl[g][c] = a;
    if (c >= 4 && c < 20)  Bm[(b0+g)*16 + (c-4)]  = a;
    else if (c >= 20)      Cm[(b0+g)*16 + (c-20)] = a;
  }
  __syncthreads();
  // GEMM3: softplus(delta) + dxs -> sdx
  {
    int d = t & 127, hi = t >> 7;
#pragma unroll
    for (int gg = 0; gg < G/2; gg++) {
      int g = hi*(G/2) + gg;
      int b = b0 + g;
      float dt = sdbl[g][0]*dtw[d]     + sdbl[g][1]*dtw[128+d]
               + sdbl[g][2]*dtw[256+d] + sdbl[g][3]*dtw[384+d];
      float dv = fmaxf(dt, 0.f) + log1pf(expf(-fabsf(dt)));  // softplus
      delta[(size_t)b*128 + d] = dv;
      sdx[g][d] = dv * sxs[g][d];
    }
  }
  __syncthreads();
  // dxh2 pack + gates (one node per wave per step, wave-local)
  for (int i = t; i < G*64; i += 256) {
    int g = i >> 6, d = i & 63;
    h2 pk;
    pk.x = (_Float16)sdx[g][d];
    pk.y = (_Float16)sdx[g][d + 64];
    ((h2*)(dxh2 + ((size_t)(b0+g) << 7)))[d] = pk;
  }
  int wid = t >> 6, lane = t & 63;
#pragma unroll
  for (int s = 0; s < 2; s++) {
    int g = wid*2 + s;
    int b = b0 + g;
    float da = sdx[g][lane], db = sdx[g][lane + 64];
    float4 pr;
    pr.x = da*iaw[2*lane]   + db*iaw[2*(lane+64)];
    pr.y = da*iaw[2*lane+1] + db*iaw[2*(lane+64)+1];
    pr.z = da*oaw[2*lane]   + db*oaw[2*(lane+64)];
    pr.w = da*oaw[2*lane+1] + db*oaw[2*(lane+64)+1];
    for (int off = 32; off >= 1; off >>= 1) {
      pr.x += __shfl_down(pr.x, off);
      pr.y += __shfl_down(pr.y, off);
      pr.z += __shfl_down(pr.z, off);
      pr.w += __shfl_down(pr.w, off);
    }
    // 4 gumbels on 4 parallel lanes; bit-identical tf2x32 inputs
    float gsel = 0.f;
    if (lane < 4) {
      uint32_t kk0 = (lane < 2) ? ki0 : ko0;
      uint32_t kk1 = (lane < 2) ? ki1 : ko1;
      gsel = gumbel32(kk0, kk1, 2u*(uint32_t)b + (uint32_t)(lane & 1));
    }
    float g0 = __shfl(gsel, 0), g1 = __shfl(gsel, 1);
    float g2 = __shfl(gsel, 2), g3 = __shfl(gsel, 3);
    if (lane == 0) {
      float BC = 0.f;
      for (int n = 0; n < 16; n++) BC += sdbl[g][4+n] * sdbl[g][20+n];
      float li0 = BC*pr.x + iab[0], li1 = BC*pr.y + iab[1];
      float lo0 = BC*pr.z + oab[0], lo1 = BC*pr.w + oab[1];
      inp[b]  = (li0 + g0 >= li1 + g1) ? 1.0f : 0.0f;
      outp[b] = (lo0 + g2 >= lo1 + g3) ? 1.0f : 0.0f;
    }
  }
}

// ---------- spmm0 + layer-1 update + deg1 + layer-2 self-term ----------
// ONE WAVE PER NODE (R2 structure). Neighbor loop PADDED to a multiple of 4
// (zero-coef slots; dxh2/Bm are written for ALL nodes so padded loads are
// finite and contribute exact +0) -> branch-free 4-wide bodies the compiler
// can software-pipeline. NOTE: do NOT cap VGPRs via __launch_bounds__ min-waves
// (R8: forced cap -> 319 MB scratch spill traffic, 78us/dispatch). ~84 VGPR
// natural -> ~6 waves/SIMD is this algorithm's occupancy ceiling.
__global__ __launch_bounds__(256) void k_spmm0f(
    const int* __restrict__ cnt, const int* __restrict__ csr_col,
    const float* __restrict__ inp, const float* __restrict__ outp,
    const float* __restrict__ delta, const _Float16* __restrict__ dxh2,
    const float* __restrict__ Bm, const float* __restrict__ Cm,
    const float* __restrict__ Amat,
    _Float16* __restrict__ s_out, float* __restrict__ dinv1,
    float* __restrict__ y2p) {
  int t = threadIdx.x, wid = t >> 6, lane = t & 63;
  int v = (blockIdx.x << 2) + wid;
  int deg = min(cnt[v], CAP);
  float inpv = inp[v];      // hoisted: in flight during the gather loop
  float outpv = outp[v];
  int   creg = 0;
  float cfreg = 0.f, gl = 0.f;
  if (lane < deg) {
    creg = csr_col[(v << 6) + lane];
    cfreg = 1.0f / sqrtf((float)min(cnt[creg], CAP) + 1.0f);
    gl = inp[creg];
  }
  float degs = gl;
#pragma unroll
  for (int off = 32; off >= 1; off >>= 1) degs += __shfl_xor(degs, off);
  int d0 = lane, d1 = lane + 64;
  float dv = 1.0f / sqrtf((float)deg + 1.0f);
  h2 pkv = ((const h2*)(dxh2 + ((size_t)v << 7)))[d0];
  float dx0 = (float)pkv.x, dx1 = (float)pkv.y;
  // self-node B row (fp32)
  float Bf[16];
  {
    const float4* p = (const float4*)(Bm + ((size_t)v << 4));
    float4 q0 = p[0], q1 = p[1], q2 = p[2], q3 = p[3];
    Bf[0]=q0.x; Bf[1]=q0.y; Bf[2]=q0.z; Bf[3]=q0.w;
    Bf[4]=q1.x; Bf[5]=q1.y; Bf[6]=q1.z; Bf[7]=q1.w;
    Bf[8]=q2.x; Bf[9]=q2.y; Bf[10]=q2.z; Bf[11]=q2.w;
    Bf[12]=q3.x; Bf[13]=q3.y; Bf[14]=q3.z; Bf[15]=q3.w;
  }
  float a0[16], a1[16];
  {
    float dw = dv * dv;
    float c0 = dw * dx0, c1 = dw * dx1;
#pragma unroll
    for (int n = 0; n < 16; n++) { a0[n] = c0*Bf[n]; a1[n] = c1*Bf[n]; }
  }
  int jmax = (deg + 3) & ~3;   // padded: cf=0 slots are exact no-ops
#pragma unroll 4
  for (int j = 0; j < jmax; j++) {
    int   c  = rdlane_i(creg, j);          // SGPR-uniform neighbor id (0 on pad)
    float cf = rdlane_f(cfreg, j);         // 0 on pad
    float coef = dv * cf;
    h2 pk = ((const h2*)(dxh2 + ((size_t)c << 7)))[d0];
    const float4* bp = (const float4*)(Bm + ((size_t)c << 4));  // uniform -> s_load
    float4 B0 = bp[0], B1 = bp[1], B2 = bp[2], B3 = bp[3];
    float e0 = coef * (float)pk.x;
    float e1 = coef * (float)pk.y;
    a0[0]+=e0*B0.x; a0[1]+=e0*B0.y; a0[2]+=e0*B0.z; a0[3]+=e0*B0.w;
    a0[4]+=e0*B1.x; a0[5]+=e0*B1.y; a0[6]+=e0*B1.z; a0[7]+=e0*B1.w;
    a0[8]+=e0*B2.x; a0[9]+=e0*B2.y; a0[10]+=e0*B2.z; a0[11]+=e0*B2.w;
    a0[12]+=e0*B3.x; a0[13]+=e0*B3.y; a0[14]+=e0*B3.z; a0[15]+=e0*B3.w;
    a1[0]+=e1*B0.x; a1[1]+=e1*B0.y; a1[2]+=e1*B0.z; a1[3]+=e1*B0.w;
    a1[4]+=e1*B1.x; a1[5]+=e1*B1.y; a1[6]+=e1*B1.z; a1[7]+=e1*B1.w;
    a1[8]+=e1*B2.x; a1[9]+=e1*B2.y; a1[10]+=e1*B2.z; a1[11]+=e1*B2.w;
    a1[12]+=e1*B3.x; a1[13]+=e1*B3.y; a1[14]+=e1*B3.z; a1[15]+=e1*B3.w;
  }
  float de0 = delta[(size_t)v*128 + d0], de1 = delta[(size_t)v*128 + d1];
  const float4* A0p = (const float4*)(Amat + (d0 << 4));
  const float4* A1p = (const float4*)(Amat + (d1 << 4));
  const float4* Cp  = (const float4*)(Cm + ((size_t)v << 4));
  float d1v = 1.0f / sqrtf(outpv*degs + 1.0f);
  if (lane == 0) dinv1[v] = d1v;
  float dw1 = d1v * d1v;
  float y0 = 0.f, y1 = 0.f, BvC = 0.f;
  _Float16 sh0[16], sh1[16];
#pragma unroll
  for (int q = 0; q < 4; q++) {
    float4 Aq0 = A0p[q], Aq1 = A1p[q], Cq = Cp[q];
    float A0a[4] = {Aq0.x, Aq0.y, Aq0.z, Aq0.w};
    float A1a[4] = {Aq1.x, Aq1.y, Aq1.z, Aq1.w};
    float Ca[4]  = {Cq.x, Cq.y, Cq.z, Cq.w};
#pragma unroll
    for (int i = 0; i < 4; i++) {
      int n = 4*q + i;
      float E0 = expf(de0 * A0a[i]);
      float E1 = expf(de1 * A1a[i]);
      float s0 = E0*a0[n] + dx0*Bf[n];
      float s1 = E1*a1[n] + dx1*Bf[n];
      y0 += E0*s0*Ca[i];
      y1 += E1*s1*Ca[i];
      BvC += Bf[n]*Ca[i];
      sh0[n] = (_Float16)s0;
      sh1[n] = (_Float16)s1;
    }
  }
  y0 = dw1*y0 + dx0*BvC;
  y1 = dw1*y1 + dx1*BvC;
  if (inpv != 0.f) {
    h8 P00, P01, P10, P11;
#pragma unroll
    for (int i = 0; i < 8; i++) {
      P00[i] = sh0[i]; P01[i] = sh0[8+i];
      P10[i] = sh1[i]; P11[i] = sh1[8+i];
    }
    h8* op = (h8*)(s_out + ((size_t)v << 11));
    op[2*lane]           = P00;
    op[2*lane + 1]       = P01;
    op[128 + 2*lane]     = P10;
    op[128 + 2*lane + 1] = P11;
  }
  y2p[(size_t)v*128 + d0] = y0;
  y2p[(size_t)v*128 + d1] = y1;
}

// ---------- gated spmm1 + layer-2 + output projection ----------
// ONE WAVE PER NODE. Per-wave LDS compaction of ACTIVE neighbors (wave-local
// atomics, no barriers) -> dense branch-free padded loop (pads re-read the
// first ACTIVE row with coef 0: written data, L2-hot, exact no-op).
__global__ __launch_bounds__(256) void k_spmm1fo(
    const int* __restrict__ cnt, const int* __restrict__ csr_col,
    const float* __restrict__ dinv1,
    const float* __restrict__ inp, const float* __restrict__ outp,
    const float* __restrict__ delta,
    const float* __restrict__ Cm, const float* __restrict__ Amat,
    const _Float16* __restrict__ s_in, const float* __restrict__ y2p,
    const float* __restrict__ xs, const float* __restrict__ rres,
    const float* __restrict__ Dv, const _Float16* __restrict__ woT,
    float* __restrict__ out) {
  __shared__ float ty[4][128];
  __shared__ int   scn[4];
  __shared__ int   scc[4][CAP];
  __shared__ float scf[4][CAP];
  int t = threadIdx.x, wid = t >> 6, lane = t & 63;
  int v = (blockIdx.x << 2) + wid;
  int deg = (outp[v] != 0.f) ? min(cnt[v], CAP) : 0;
  if (lane == 0) scn[wid] = 0;          // same-wave LDS ordering: write < atomics
  if (lane < deg) {
    int c = csr_col[(v << 6) + lane];
    float g = inp[c];
    if (g != 0.f) {
      int p = atomicAdd(&scn[wid], 1);  // wave-local compaction
      scc[wid][p] = c;
      scf[wid][p] = dinv1[c];
    }
  }
  asm volatile("s_waitcnt lgkmcnt(0)" ::: "memory");
  int nact = scn[wid];
  int   creg = 0;
  float cfreg = 0.f;
  if (nact > 0) {
    creg = scc[wid][(lane < nact) ? lane : 0];  // pad slots -> first ACTIVE row
    if (lane < nact) cfreg = scf[wid][lane];    // pad coef = 0
  }
  int d0 = lane, d1 = lane + 64;
  float y0 = 0.f, y1 = 0.f;
  if (nact > 0) {
    float dvv = dinv1[v];
    float a0[16], a1[16];
#pragma unroll
    for (int n = 0; n < 16; n++) { a0[n] = 0.f; a1[n] = 0.f; }
    int jmax = (nact + 3) & ~3;
#pragma unroll 4
    for (int j = 0; j < jmax; j++) {
      int   c  = rdlane_i(creg, j);
      float cf = rdlane_f(cfreg, j);
      float coef = dvv * cf;
      const h8* rp = (const h8*)(s_in + ((size_t)c << 11));
      h8 n00 = rp[2*lane], n01 = rp[2*lane+1];
      h8 n10 = rp[128 + 2*lane], n11 = rp[128 + 2*lane+1];
      a0[0]+=coef*(float)n00[0]; a0[1]+=coef*(float)n00[1];
      a0[2]+=coef*(float)n00[2]; a0[3]+=coef*(float)n00[3];
      a0[4]+=coef*(float)n00[4]; a0[5]+=coef*(float)n00[5];
      a0[6]+=coef*(float)n00[6]; a0[7]+=coef*(float)n00[7];
      a0[8]+=coef*(float)n01[0]; a0[9]+=coef*(float)n01[1];
      a0[10]+=coef*(float)n01[2]; a0[11]+=coef*(float)n01[3];
      a0[12]+=coef*(float)n01[4]; a0[13]+=coef*(float)n01[5];
      a0[14]+=coef*(float)n01[6]; a0[15]+=coef*(float)n01[7];
      a1[0]+=coef*(float)n10[0]; a1[1]+=coef*(float)n10[1];
      a1[2]+=coef*(float)n10[2]; a1[3]+=coef*(float)n10[3];
      a1[4]+=coef*(float)n10[4]; a1[5]+=coef*(float)n10[5];
      a1[6]+=coef*(float)n10[6]; a1[7]+=coef*(float)n10[7];
      a1[8]+=coef*(float)n11[0]; a1[9]+=coef*(float)n11[1];
      a1[10]+=coef*(float)n11[2]; a1[11]+=coef*(float)n11[3];
      a1[12]+=coef*(float)n11[4]; a1[13]+=coef*(float)n11[5];
      a1[14]+=coef*(float)n11[6]; a1[15]+=coef*(float)n11[7];
    }
    float de0 = delta[(size_t)v*128 + d0], de1 = delta[(size_t)v*128 + d1];
    const float4* A0p = (const float4*)(Amat + (d0 << 4));
    const float4* A1p = (const float4*)(Amat + (d1 << 4));
    const float4* Cp  = (const float4*)(Cm + ((size_t)v << 4));
#pragma unroll
    for (int q = 0; q < 4; q++) {
      float4 Aq0 = A0p[q], Aq1 = A1p[q], Cq = Cp[q];
      float A0a[4] = {Aq0.x, Aq0.y, Aq0.z, Aq0.w};
      float A1a[4] = {Aq1.x, Aq1.y, Aq1.z, Aq1.w};
      float Ca[4]  = {Cq.x, Cq.y, Cq.z, Cq.w};
#pragma unroll
      for (int i = 0; i < 4; i++) {
        int n = 4*q + i;
        y0 += expf(de0*A0a[i]) * a0[n] * Ca[i];
        y1 += expf(de1*A1a[i]) * a1[n] * Ca[i];
      }
    }
  }
  float t0 = (y0 + y2p[(size_t)v*128 + d0] + xs[(size_t)v*128 + d0]*Dv[d0]) * rres[(size_t)v*128 + d0];
  float t1 = (y1 + y2p[(size_t)v*128 + d1] + xs[(size_t)v*128 + d1]*Dv[d1]) * rres[(size_t)v*128 + d1];
  ty[wid][d0] = t0;
  ty[wid][d1] = t1;
  asm volatile("s_waitcnt lgkmcnt(0)" ::: "memory");   // wave's ty writes complete
  __builtin_amdgcn_sched_barrier(0);
  // projection: lane = oc; ty broadcast reads (b128) + 16 h8 woT row loads (L1-resident)
  float acc = 0.f;
  const float4* tyv = (const float4*)&ty[wid][0];
  const h8* wrow = (const h8*)(woT + ((size_t)lane << 7));
#pragma unroll
  for (int ch = 0; ch < 16; ch++) {
    h8 wv = wrow[ch];
    float4 u0 = tyv[2*ch], u1 = tyv[2*ch+1];
    acc += u0.x*(float)wv[0] + u0.y*(float)wv[1] + u0.z*(float)wv[2] + u0.w*(float)wv[3]
         + u1.x*(float)wv[4] + u1.y*(float)wv[5] + u1.z*(float)wv[6] + u1.w*(float)wv[7];
  }
  out[(size_t)v*64 + lane] = acc;
}

extern "C" void kernel_launch(void* const* d_in, const int* in_sizes, int n_in,
                              void* d_out, int out_size, void* d_ws, size_t ws_size,
                              hipStream_t stream) {
  const float* x    = (const float*)d_in[0];
  const float* ipw  = (const float*)d_in[1];
  const float* xpw  = (const float*)d_in[2];
  const float* dtw  = (const float*)d_in[3];
  const float* alog = (const float*)d_in[4];
  const float* Dv   = (const float*)d_in[5];
  const float* wout = (const float*)d_in[6];
  const float* iaw  = (const float*)d_in[7];
  const float* iab  = (const float*)d_in[8];
  const float* oaw  = (const float*)d_in[9];
  const float* oab  = (const float*)d_in[10];
  const int*   ei   = (const int*)d_in[11];
  (void)in_sizes; (void)n_in; (void)out_size; (void)ws_size;

  float* W = (float*)d_ws;
  size_t o = 0;
  float* xs    = W + o; o += (size_t)NN*128;
  float* rres  = W + o; o += (size_t)NN*128;
  float* delta = W + o; o += (size_t)NN*128;
  float* y2p   = W + o; o += (size_t)NN*128;
  float* Bm    = W + o; o += (size_t)NN*16;
  float* Cm    = W + o; o += (size_t)NN*16;
  float* Amat  = W + o; o += 2048;
  float* dinv1 = W + o; o += NN;
  float* inp   = W + o; o += NN;
  float* outp  = W + o; o += NN;
  _Float16* dxh2 = (_Float16*)(W + o); o += (size_t)NN*64;   // 2 MB
  o += (size_t)NN*8;                                          // (reserved slot)
  _Float16* woT  = (_Float16*)(W + o); o += 4096;            // 16 KB (8192 h, transposed [oc][d])
  _Float16* stA  = (_Float16*)(W + o); o += (size_t)NN*1024; // fp16 state1, 32 MB
  int* cnt     = (int*)(W + o);
  int* csr_col = cnt + NN;

  uint32_t ki0, ki1, ko0, ko1;
  tf2x32(0u, 42u, 0u, 0u, ki0, ki1);
  tf2x32(0u, 42u, 0u, 1u, ko0, ko1);

  // zero CSR counters; scatter is fused into k_nodeprep
  hipMemsetAsync(cnt, 0, NN*sizeof(int), stream);

  // per-node precompute + layer-0 gates + Amat + woT + edge scatter
  k_nodeprep<<<NN/G, 256, 0, stream>>>(x, ipw, xpw, dtw, iaw, iab, oaw, oab,
                                       alog, wout, ei, ki0, ki1, ko0, ko1,
                                       xs, rres, delta, dxh2, Bm, Cm,
                                       inp, outp, Amat, woT, cnt, csr_col);

  // spmm0 + layer-1 update + deg1 + layer-2 self-term; one wave/node, padded pipeline
  k_spmm0f<<<NN/4, 256, 0, stream>>>(cnt, csr_col, inp, outp,
                                     delta, dxh2, Bm, Cm, Amat,
                                     stA, dinv1, y2p);

  // gated spmm1 + layer-2 + output projection; one wave/node, compacted dense loop
  k_spmm1fo<<<NN/4, 256, 0, stream>>>(cnt, csr_col, dinv1, inp, outp,
                                      delta, Cm, Amat, stA, y2p,
                                      xs, rres, Dv, woT, (float*)d_out);
}